// Round 5
// baseline (668.567 us; speedup 1.0000x reference)
//
#include <hip/hip_runtime.h>
#include <math.h>

#define NB     2
#define SEQ    2048
#define NHEAD  12
#define DMODEL 768
#define SPAN2  1024
#define SCALEF 0.07216878364870323f   // 1/sqrt(192)

typedef unsigned short ushort;
typedef unsigned int   uint;
typedef __attribute__((ext_vector_type(8))) short  bh8;   // 8 x bf16
typedef __attribute__((ext_vector_type(4))) float  f32x4; // MFMA C/D frag
typedef __attribute__((ext_vector_type(4))) unsigned short us4;

__device__ inline ushort f2bf(float x) {            // RNE f32 -> bf16
    uint u = __builtin_bit_cast(uint, x);
    u += 0x7FFFu + ((u >> 16) & 1u);
    return (ushort)(u >> 16);
}
__device__ inline float b2f(ushort h) {
    uint u = ((uint)h) << 16;
    return __builtin_bit_cast(float, u);
}

// ---------------------------------------------------------------------------
// Multi-segment f32 -> bf16 convert.
// ---------------------------------------------------------------------------
struct CvtArgs {
    const float* src[8];
    ushort*      dst[8];
    int          n[8];
};

__global__ __launch_bounds__(256) void cvt_bf16(CvtArgs a)
{
    const int seg = blockIdx.y;
    const int i   = (blockIdx.x * 256 + threadIdx.x) * 8;
    if (i >= a.n[seg]) return;
    const float4* s = (const float4*)(a.src[seg] + i);
    const float4 x = s[0], y = s[1];
    bh8 o;
    o[0] = (short)f2bf(x.x); o[1] = (short)f2bf(x.y);
    o[2] = (short)f2bf(x.z); o[3] = (short)f2bf(x.w);
    o[4] = (short)f2bf(y.x); o[5] = (short)f2bf(y.y);
    o[6] = (short)f2bf(y.z); o[7] = (short)f2bf(y.w);
    *(bh8*)(a.dst[seg] + i) = o;
}

// ---------------------------------------------------------------------------
// LDS-free MFMA projection GEMM:  out = (X @ W^T + b1 + b2) * scale
// Block = 32(M) x 64(N) tile, 4 waves: wave (wr=w&1 -> 16-row strip,
// wc=w>>1 -> 32-col half).  Grid (Mrows/32, NHEAD).
// ---------------------------------------------------------------------------
__global__ __launch_bounds__(256) void proj_mfma(
    const ushort* __restrict__ X, const ushort* __restrict__ W,
    const float* __restrict__ b1, const float* __restrict__ b2,
    float scale, int rowsPerBatch,
    ushort* __restrict__ out, ushort* __restrict__ outT)
{
    const int r0 = blockIdx.x * 32;
    const int n  = blockIdx.y;
    const int c0 = n * 64;
    const int tid  = threadIdx.x;
    const int w    = tid >> 6;
    const int lane = tid & 63;
    const int lo   = lane & 15;
    const int hi8  = (lane >> 4) * 8;
    const int g4   = (lane >> 4) * 4;
    const int wr   = w & 1;
    const int wc   = w >> 1;

    const ushort* arow = X + (size_t)(r0 + wr * 16 + lo) * DMODEL;

    f32x4 acc[2] = {};
    for (int k0 = 0; k0 < DMODEL; k0 += 64) {
        const bh8 a0 = *(const bh8*)&arow[k0 + hi8];
        const bh8 a1 = *(const bh8*)&arow[k0 + 32 + hi8];
        #pragma unroll
        for (int ct = 0; ct < 2; ++ct) {
            const ushort* wrow = W + (size_t)(c0 + wc * 32 + ct * 16 + lo) * DMODEL + k0;
            const bh8 wb0 = *(const bh8*)&wrow[hi8];
            const bh8 wb1 = *(const bh8*)&wrow[32 + hi8];
            acc[ct] = __builtin_amdgcn_mfma_f32_16x16x32_bf16(a0, wb0, acc[ct], 0, 0, 0);
            acc[ct] = __builtin_amdgcn_mfma_f32_16x16x32_bf16(a1, wb1, acc[ct], 0, 0, 0);
        }
    }

    const int rbase = r0 + wr * 16 + g4;
    const int bb  = rbase / rowsPerBatch;
    const int rr0 = rbase - bb * rowsPerBatch;
    #pragma unroll
    for (int ct = 0; ct < 2; ++ct) {
        const int d = wc * 32 + ct * 16 + lo;
        const int c = c0 + d;
        const float badd = (b1 ? b1[c] : 0.f) + (b2 ? b2[c] : 0.f);
        if (out) {
            #pragma unroll
            for (int reg = 0; reg < 4; ++reg)
                out[(((size_t)bb * NHEAD + n) * rowsPerBatch + rr0 + reg) * 64 + d] =
                    f2bf((acc[ct][reg] + badd) * scale);
        }
        if (outT) {
            us4 o;
            #pragma unroll
            for (int reg = 0; reg < 4; ++reg)
                o[reg] = f2bf((acc[ct][reg] + badd) * scale);
            *(us4*)&outT[(((size_t)bb * NHEAD + n) * 64 + d) * rowsPerBatch + rr0] = o;
        }
    }
}

// ---------------------------------------------------------------------------
// Assembled bias table:  bias[bn][i][j] (bf16) =
//   [i>0 && j>0] * ( q_i . posk[clip(i-j+512)] + k_j . posq[clip(i-j+512)] )
//   - 1e6*(1 - mask[b][j])
// Per 64x64 tile, delta window t = (i-i0)-(j-j0)+63 in [0,126]:
//   T1[il][t] = q . posk_band, T2[jl][t] = k . posq_band  (band MFMAs),
// then gather-add from LDS, coalesced 32B stores.
// Grid (32 j-tiles, 32 i-tiles, 24 bn), block 256 = 4 waves.
// ---------------------------------------------------------------------------
__global__ __launch_bounds__(256) void bias_tile(
    const ushort* __restrict__ qh, const ushort* __restrict__ kh,
    const ushort* __restrict__ posk, const ushort* __restrict__ posq,
    const float* __restrict__ mask, ushort* __restrict__ biasT)
{
    __shared__ ushort T1s[64 * 132];
    __shared__ ushort T2s[64 * 132];
    __shared__ float  mlds[64];

    const int bn = blockIdx.z;
    const int n  = bn % NHEAD;
    const int b  = bn / NHEAD;
    const int i0 = blockIdx.y * 64;
    const int j0 = blockIdx.x * 64;
    const int tid  = threadIdx.x;
    const int w    = tid >> 6;
    const int lane = tid & 63;
    const int lo   = lane & 15;
    const int hi8  = (lane >> 4) * 8;
    const int g4   = (lane >> 4) * 4;
    const int w16  = w * 16;
    const int d0   = i0 - j0 + 449;          // delta at t=0 (= i0-j0+512-63)

    if (tid < 64)
        mlds[tid] = -1e6f * (1.f - mask[(size_t)b * SEQ + j0 + tid]);

    const ushort* qrow = qh + ((size_t)bn * SEQ + i0 + w16 + lo) * 64;
    const bh8 qa0 = *(const bh8*)&qrow[hi8];
    const bh8 qa1 = *(const bh8*)&qrow[32 + hi8];
    const ushort* krow = kh + ((size_t)bn * SEQ + j0 + w16 + lo) * 64;
    const bh8 ka0 = *(const bh8*)&krow[hi8];
    const bh8 ka1 = *(const bh8*)&krow[32 + hi8];

    const ushort* pkh = posk + (size_t)n * SPAN2 * 64;
    const ushort* pqh = posq + (size_t)n * SPAN2 * 64;

    #pragma unroll
    for (int ct = 0; ct < 8; ++ct) {
        int r = d0 + ct * 16 + lo;
        r = r < 0 ? 0 : (r > SPAN2 - 1 ? SPAN2 - 1 : r);
        const ushort* pk = pkh + (size_t)r * 64;
        const bh8 pk0 = *(const bh8*)&pk[hi8];
        const bh8 pk1 = *(const bh8*)&pk[32 + hi8];
        f32x4 z1 = {};
        z1 = __builtin_amdgcn_mfma_f32_16x16x32_bf16(qa0, pk0, z1, 0, 0, 0);
        z1 = __builtin_amdgcn_mfma_f32_16x16x32_bf16(qa1, pk1, z1, 0, 0, 0);
        const ushort* pq = pqh + (size_t)r * 64;
        const bh8 pq0 = *(const bh8*)&pq[hi8];
        const bh8 pq1 = *(const bh8*)&pq[32 + hi8];
        f32x4 z2 = {};
        z2 = __builtin_amdgcn_mfma_f32_16x16x32_bf16(ka0, pq0, z2, 0, 0, 0);
        z2 = __builtin_amdgcn_mfma_f32_16x16x32_bf16(ka1, pq1, z2, 0, 0, 0);
        #pragma unroll
        for (int reg = 0; reg < 4; ++reg) {
            T1s[(w16 + g4 + reg) * 132 + ct * 16 + lo] = f2bf(z1[reg]);
            T2s[(w16 + g4 + reg) * 132 + ct * 16 + lo] = f2bf(z2[reg]);
        }
    }
    __syncthreads();

    // epilogue: thread -> row r = tid>>2 (0..63), cols cs..cs+15
    const int r  = tid >> 2;
    const int cs = (tid & 3) * 16;
    const int gi = i0 + r;
    bh8 o0, o1;
    #pragma unroll
    for (int e = 0; e < 16; ++e) {
        const int jl = cs + e;
        const int t  = r - jl + 63;
        float v = 0.f;
        if (gi > 0 && (j0 + jl) > 0)
            v = b2f(T1s[r * 132 + t]) + b2f(T2s[jl * 132 + t]);
        v += mlds[jl];
        if (e < 8) o0[e] = (short)f2bf(v); else o1[e - 8] = (short)f2bf(v);
    }
    ushort* dst = biasT + ((size_t)bn * SEQ + gi) * SEQ + j0 + cs;
    *(bh8*)dst       = o0;
    *(bh8*)(dst + 8) = o1;
}

// ---------------------------------------------------------------------------
// MFMA flash attention v4: bias (incl. mask + CLS-zeroing) from assembled
// table, read fully coalesced. BM=32; wave pair splits the j range
// (waves 0/1 -> j<1024, waves 2/3 -> j>=1024), LDS merge at the end.
// Grid (SEQ/32, NHEAD, NB), block 256. Zero barriers in the main loop.
// ---------------------------------------------------------------------------
__global__ __launch_bounds__(256) void attn_mfma4(
    const ushort* __restrict__ qh, const ushort* __restrict__ kh,
    const ushort* __restrict__ vht, const ushort* __restrict__ biasT,
    float* __restrict__ attn)
{
    __shared__ ushort Ps[4][16][68];       // per-wave P tile
    __shared__ float  mbuf[2][64][27];     // merge buffer (padded stride)

    const int b  = blockIdx.z;
    const int n  = blockIdx.y;
    const int i0 = blockIdx.x * 32;
    const int bn = b * NHEAD + n;
    const int tid  = threadIdx.x;
    const int w    = tid >> 6;
    const int lane = tid & 63;
    const int lo   = lane & 15;
    const int hi8  = (lane >> 4) * 8;
    const int g4   = (lane >> 4) * 4;
    const int ibase  = i0 + (w & 1) * 16;
    const int jstart = (w >> 1) * (SEQ / 2);

    const ushort* qrow = qh + ((size_t)bn * SEQ + ibase + lo) * 64;
    const bh8 qa0 = *(const bh8*)&qrow[hi8];
    const bh8 qa1 = *(const bh8*)&qrow[32 + hi8];

    const ushort* khb = kh  + ((size_t)bn * SEQ + jstart) * 64;
    const ushort* vtb = vht + (size_t)bn * 64 * SEQ + jstart;

    const ushort* biasRow[4];
    #pragma unroll
    for (int reg = 0; reg < 4; ++reg)
        biasRow[reg] = biasT + ((size_t)bn * SEQ + ibase + g4 + reg) * SEQ + jstart;

    f32x4 accPV[4] = {};
    float mrow[4] = {-1e30f, -1e30f, -1e30f, -1e30f};
    float lrow[4] = {0.f, 0.f, 0.f, 0.f};

    for (int jr = 0; jr < SEQ / 2; jr += 64) {
        // ---- bias reads (dense, mask & CLS baked in) ----
        float biasv[4][4];
        #pragma unroll
        for (int reg = 0; reg < 4; ++reg)
            #pragma unroll
            for (int ct = 0; ct < 4; ++ct)
                biasv[reg][ct] = b2f(biasRow[reg][jr + ct * 16 + lo]);

        // ---- S = Q K^T ----
        f32x4 accS[4];
        #pragma unroll
        for (int ct = 0; ct < 4; ++ct) {
            const ushort* kr = khb + (size_t)(jr + ct * 16 + lo) * 64;
            const bh8 kb0 = *(const bh8*)&kr[hi8];
            const bh8 kb1 = *(const bh8*)&kr[32 + hi8];
            f32x4 z = {};
            z = __builtin_amdgcn_mfma_f32_16x16x32_bf16(qa0, kb0, z, 0, 0, 0);
            accS[ct] = __builtin_amdgcn_mfma_f32_16x16x32_bf16(qa1, kb1, z, 0, 0, 0);
        }

        // ---- online softmax on C-frag layout ----
        float corr[4];
        #pragma unroll
        for (int reg = 0; reg < 4; ++reg) {
            float s[4], rmax = -1e30f;
            #pragma unroll
            for (int ct = 0; ct < 4; ++ct) {
                const float v = accS[ct][reg] + biasv[reg][ct];
                s[ct] = v;
                rmax = fmaxf(rmax, v);
            }
            rmax = fmaxf(rmax, __shfl_xor(rmax, 1));
            rmax = fmaxf(rmax, __shfl_xor(rmax, 2));
            rmax = fmaxf(rmax, __shfl_xor(rmax, 4));
            rmax = fmaxf(rmax, __shfl_xor(rmax, 8));
            const float mnew = fmaxf(mrow[reg], rmax);
            const float cc   = __expf(mrow[reg] - mnew);
            float psum = 0.f;
            #pragma unroll
            for (int ct = 0; ct < 4; ++ct) {
                const float p = __expf(s[ct] - mnew);
                psum += p;
                Ps[w][g4 + reg][ct * 16 + lo] = f2bf(p);
            }
            psum += __shfl_xor(psum, 1);
            psum += __shfl_xor(psum, 2);
            psum += __shfl_xor(psum, 4);
            psum += __shfl_xor(psum, 8);
            lrow[reg] = lrow[reg] * cc + psum;
            mrow[reg] = mnew;
            corr[reg] = cc;
        }

        // ---- PV: A = P (wave-private LDS), B = V^T rows (global) ----
        {
            const bh8 pa0 = *(const bh8*)&Ps[w][lo][hi8];
            const bh8 pa1 = *(const bh8*)&Ps[w][lo][32 + hi8];
            #pragma unroll
            for (int dt = 0; dt < 4; ++dt) {
                const ushort* vr = vtb + (size_t)(dt * 16 + lo) * SEQ + jr;
                const bh8 vb0 = *(const bh8*)&vr[hi8];
                const bh8 vb1 = *(const bh8*)&vr[32 + hi8];
                f32x4 a = accPV[dt];
                #pragma unroll
                for (int reg = 0; reg < 4; ++reg) a[reg] *= corr[reg];
                a = __builtin_amdgcn_mfma_f32_16x16x32_bf16(pa0, vb0, a, 0, 0, 0);
                accPV[dt] = __builtin_amdgcn_mfma_f32_16x16x32_bf16(pa1, vb1, a, 0, 0, 0);
            }
        }
    }

    // ---- merge the two j-halves (wave w <- wave w+2) ----
    if (w >= 2) {
        float* dst = &mbuf[w - 2][lane][0];
        #pragma unroll
        for (int dt = 0; dt < 4; ++dt)
            #pragma unroll
            for (int reg = 0; reg < 4; ++reg)
                dst[dt * 4 + reg] = accPV[dt][reg];
        #pragma unroll
        for (int reg = 0; reg < 4; ++reg) {
            dst[16 + reg] = mrow[reg];
            dst[20 + reg] = lrow[reg];
        }
    }
    __syncthreads();
    if (w < 2) {
        const float* src = &mbuf[w][lane][0];
        float a1[4], a2[4];
        #pragma unroll
        for (int reg = 0; reg < 4; ++reg) {
            const float m2 = src[16 + reg];
            const float l2 = src[20 + reg];
            const float mm = fmaxf(mrow[reg], m2);
            a1[reg] = __expf(mrow[reg] - mm);
            a2[reg] = __expf(m2 - mm);
            lrow[reg] = lrow[reg] * a1[reg] + l2 * a2[reg];
        }
        #pragma unroll
        for (int reg = 0; reg < 4; ++reg) {
            const int i = i0 + w * 16 + g4 + reg;
            const float inv = 1.f / lrow[reg];
            #pragma unroll
            for (int dt = 0; dt < 4; ++dt) {
                const float v = accPV[dt][reg] * a1[reg] + src[dt * 4 + reg] * a2[reg];
                attn[((size_t)b * SEQ + i) * DMODEL + n * 64 + dt * 16 + lo] = v * inv;
            }
        }
    }
}

// ---------------------------------------------------------------------------
// Residual + LayerNorm, in-place on attn buffer.
// ---------------------------------------------------------------------------
__global__ __launch_bounds__(256) void resid_ln(
    float* __restrict__ attn, const float* __restrict__ query,
    const float* __restrict__ gamma, const float* __restrict__ beta)
{
    const int b = blockIdx.y;
    const int i = blockIdx.x;
    const size_t base = ((size_t)b * SEQ + i) * DMODEL;
    const int tid = threadIdx.x;

    float x[3];
    #pragma unroll
    for (int s = 0; s < 3; ++s) x[s] = attn[base + s * 256 + tid];

    float sum = x[0] + x[1] + x[2];
    float sq  = x[0]*x[0] + x[1]*x[1] + x[2]*x[2];
    #pragma unroll
    for (int off = 32; off; off >>= 1) {
        sum += __shfl_xor(sum, off);
        sq  += __shfl_xor(sq, off);
    }
    __shared__ float red[2][4];
    const int w = tid >> 6;
    if ((tid & 63) == 0) { red[0][w] = sum; red[1][w] = sq; }
    __syncthreads();
    sum = red[0][0] + red[0][1] + red[0][2] + red[0][3];
    sq  = red[1][0] + red[1][1] + red[1][2] + red[1][3];

    const float mu  = sum * (1.f / DMODEL);
    const float var = sq * (1.f / DMODEL) - mu * mu;
    const float inv = rsqrtf(var + 1e-5f);

    #pragma unroll
    for (int s = 0; s < 3; ++s) {
        const int c = s * 256 + tid;
        attn[base + c] = query[base + c] + (x[s] - mu) * inv * gamma[c] + beta[c];
    }
}

// ---------------------------------------------------------------------------
extern "C" void kernel_launch(void* const* d_in, const int* in_sizes, int n_in,
                              void* d_out, int out_size, void* d_ws, size_t ws_size,
                              hipStream_t stream)
{
    const float* query = (const float*)d_in[0];
    const float* mask  = (const float*)d_in[1];
    const float* pke   = (const float*)d_in[2];
    const float* pqe   = (const float*)d_in[3];
    const float* Wq    = (const float*)d_in[4];
    const float* bq    = (const float*)d_in[5];
    const float* Wk    = (const float*)d_in[6];
    const float* Wv    = (const float*)d_in[7];
    const float* bv    = (const float*)d_in[8];
    const float* Wpq   = (const float*)d_in[9];
    const float* bpq   = (const float*)d_in[10];
    const float* Wpk   = (const float*)d_in[11];
    const float* rwb   = (const float*)d_in[12];
    const float* gamma = (const float*)d_in[13];
    const float* beta  = (const float*)d_in[14];

    float* out = (float*)d_out;

    const int Q_N  = NB * SEQ * DMODEL;
    const int P_N  = SPAN2 * DMODEL;
    const int W_N  = DMODEL * DMODEL;
    const size_t QKV_ELEMS = (size_t)NB * NHEAD * SEQ * 64;
    const size_t POS_ELEMS = (size_t)NHEAD * SPAN2 * 64;
    const size_t TAB_ELEMS = (size_t)NB * NHEAD * SEQ * SEQ;   // 100,663,296

    ushort* xb   = (ushort*)d_ws;
    ushort* pkeb = xb   + Q_N;
    ushort* pqeb = pkeb + P_N;
    ushort* wqb  = pqeb + P_N;
    ushort* wkb  = wqb  + W_N;
    ushort* wvb  = wkb  + W_N;
    ushort* wpqb = wvb  + W_N;
    ushort* wpkb = wpqb + W_N;
    ushort* qh   = wpkb + W_N;
    ushort* kh   = qh   + QKV_ELEMS;
    ushort* vht  = kh   + QKV_ELEMS;
    ushort* pkp  = vht  + QKV_ELEMS;
    ushort* pqp  = pkp  + POS_ELEMS;
    ushort* biasT = pqp + POS_ELEMS;

    dim3 blk(256);

    CvtArgs ca;
    ca.src[0] = query; ca.dst[0] = xb;   ca.n[0] = Q_N;
    ca.src[1] = pke;   ca.dst[1] = pkeb; ca.n[1] = P_N;
    ca.src[2] = pqe;   ca.dst[2] = pqeb; ca.n[2] = P_N;
    ca.src[3] = Wq;    ca.dst[3] = wqb;  ca.n[3] = W_N;
    ca.src[4] = Wk;    ca.dst[4] = wkb;  ca.n[4] = W_N;
    ca.src[5] = Wv;    ca.dst[5] = wvb;  ca.n[5] = W_N;
    ca.src[6] = Wpq;   ca.dst[6] = wpqb; ca.n[6] = W_N;
    ca.src[7] = Wpk;   ca.dst[7] = wpkb; ca.n[7] = W_N;
    cvt_bf16<<<dim3((Q_N / 8 + 255) / 256, 8), blk, 0, stream>>>(ca);

    // projections (32-row blocks -> 6 blocks/CU)
    proj_mfma<<<dim3(128, NHEAD), blk, 0, stream>>>(xb,   wqb,  bq,  rwb, SCALEF, SEQ,   qh,  nullptr);
    proj_mfma<<<dim3(128, NHEAD), blk, 0, stream>>>(xb,   wkb,  nullptr, nullptr, 1.f, SEQ, kh, nullptr);
    proj_mfma<<<dim3(128, NHEAD), blk, 0, stream>>>(xb,   wvb,  bv,  nullptr, 1.f,   SEQ,   nullptr, vht);
    proj_mfma<<<dim3(32,  NHEAD), blk, 0, stream>>>(pkeb, wpkb, nullptr, nullptr, 1.f, SPAN2, pkp, nullptr);
    proj_mfma<<<dim3(32,  NHEAD), blk, 0, stream>>>(pqeb, wpqb, bpq, nullptr, SCALEF, SPAN2, pqp, nullptr);

    // assembled bias table (mask + CLS baked in)
    bias_tile<<<dim3(SEQ / 64, SEQ / 64, NB * NHEAD), blk, 0, stream>>>(
        qh, kh, pkp, pqp, mask, biasT);

    // attention -> d_out as [B,S,768] attn_vec (f32)
    attn_mfma4<<<dim3(SEQ / 32, NHEAD, NB), blk, 0, stream>>>(
        qh, kh, vht, biasT, out);

    // residual + LN in-place
    resid_ln<<<dim3(SEQ, NB), blk, 0, stream>>>(out, query, gamma, beta);
}

// Round 6
// 618.637 us; speedup vs baseline: 1.0807x; 1.0807x over previous
//
#include <hip/hip_runtime.h>
#include <math.h>

#define NB     2
#define SEQ    2048
#define NHEAD  12
#define DMODEL 768
#define SPAN2  1024
#define SCALEF 0.07216878364870323f   // 1/sqrt(192)

typedef unsigned short ushort;
typedef unsigned int   uint;
typedef __attribute__((ext_vector_type(8))) short  bh8;   // 8 x bf16
typedef __attribute__((ext_vector_type(4))) float  f32x4; // MFMA C/D frag
typedef __attribute__((ext_vector_type(4))) unsigned short us4;

__device__ inline ushort f2bf(float x) {            // RNE f32 -> bf16
    uint u = __builtin_bit_cast(uint, x);
    u += 0x7FFFu + ((u >> 16) & 1u);
    return (ushort)(u >> 16);
}
__device__ inline float b2f(ushort h) {
    uint u = ((uint)h) << 16;
    return __builtin_bit_cast(float, u);
}
// pack 2 f32 -> 1 dword of 2 bf16 (RNE), hardware instruction
__device__ inline uint cvtpk(float a, float b) {
    uint r;
    asm("v_cvt_pk_bf16_f32 %0, %1, %2" : "=v"(r) : "v"(a), "v"(b));
    return r;
}

// ---------------------------------------------------------------------------
// Multi-segment f32 -> bf16 convert.
// ---------------------------------------------------------------------------
struct CvtArgs {
    const float* src[8];
    ushort*      dst[8];
    int          n[8];
};

__global__ __launch_bounds__(256) void cvt_bf16(CvtArgs a)
{
    const int seg = blockIdx.y;
    const int i   = (blockIdx.x * 256 + threadIdx.x) * 8;
    if (i >= a.n[seg]) return;
    const float4* s = (const float4*)(a.src[seg] + i);
    const float4 x = s[0], y = s[1];
    bh8 o;
    o[0] = (short)f2bf(x.x); o[1] = (short)f2bf(x.y);
    o[2] = (short)f2bf(x.z); o[3] = (short)f2bf(x.w);
    o[4] = (short)f2bf(y.x); o[5] = (short)f2bf(y.y);
    o[6] = (short)f2bf(y.z); o[7] = (short)f2bf(y.w);
    *(bh8*)(a.dst[seg] + i) = o;
}

// ---------------------------------------------------------------------------
// LDS-free MFMA projection GEMM:  out = (X @ W^T + b1 + b2) * scale
// Block = 32(M) x 64(N) tile, 4 waves.  Grid (Mrows/32, NHEAD).
// ---------------------------------------------------------------------------
__global__ __launch_bounds__(256) void proj_mfma(
    const ushort* __restrict__ X, const ushort* __restrict__ W,
    const float* __restrict__ b1, const float* __restrict__ b2,
    float scale, int rowsPerBatch,
    ushort* __restrict__ out, ushort* __restrict__ outT)
{
    const int r0 = blockIdx.x * 32;
    const int n  = blockIdx.y;
    const int c0 = n * 64;
    const int tid  = threadIdx.x;
    const int w    = tid >> 6;
    const int lane = tid & 63;
    const int lo   = lane & 15;
    const int hi8  = (lane >> 4) * 8;
    const int g4   = (lane >> 4) * 4;
    const int wr   = w & 1;
    const int wc   = w >> 1;

    const ushort* arow = X + (size_t)(r0 + wr * 16 + lo) * DMODEL;

    f32x4 acc[2] = {};
    for (int k0 = 0; k0 < DMODEL; k0 += 64) {
        const bh8 a0 = *(const bh8*)&arow[k0 + hi8];
        const bh8 a1 = *(const bh8*)&arow[k0 + 32 + hi8];
        #pragma unroll
        for (int ct = 0; ct < 2; ++ct) {
            const ushort* wrow = W + (size_t)(c0 + wc * 32 + ct * 16 + lo) * DMODEL + k0;
            const bh8 wb0 = *(const bh8*)&wrow[hi8];
            const bh8 wb1 = *(const bh8*)&wrow[32 + hi8];
            acc[ct] = __builtin_amdgcn_mfma_f32_16x16x32_bf16(a0, wb0, acc[ct], 0, 0, 0);
            acc[ct] = __builtin_amdgcn_mfma_f32_16x16x32_bf16(a1, wb1, acc[ct], 0, 0, 0);
        }
    }

    const int rbase = r0 + wr * 16 + g4;
    const int bb  = rbase / rowsPerBatch;
    const int rr0 = rbase - bb * rowsPerBatch;
    #pragma unroll
    for (int ct = 0; ct < 2; ++ct) {
        const int d = wc * 32 + ct * 16 + lo;
        const int c = c0 + d;
        const float badd = (b1 ? b1[c] : 0.f) + (b2 ? b2[c] : 0.f);
        if (out) {
            #pragma unroll
            for (int reg = 0; reg < 4; ++reg)
                out[(((size_t)bb * NHEAD + n) * rowsPerBatch + rr0 + reg) * 64 + d] =
                    f2bf((acc[ct][reg] + badd) * scale);
        }
        if (outT) {
            us4 o;
            #pragma unroll
            for (int reg = 0; reg < 4; ++reg)
                o[reg] = f2bf((acc[ct][reg] + badd) * scale);
            *(us4*)&outT[(((size_t)bb * NHEAD + n) * 64 + d) * rowsPerBatch + rr0] = o;
        }
    }
}

// ---------------------------------------------------------------------------
// Fused MFMA flash attention v5 (single S x S pass):
//  - bn-clustered XCD swizzle: each XCD owns 3 (b,n) pairs -> K/V/pos L2-hot
//  - bias bands computed in-kernel per 64x64 tile, stored TRANSPOSED in LDS
//    (T[u][row]) via v_cvt_pk_bf16_f32 + ds_write_b64
//  - Q/K/V^T/pos MFMA operands all contiguous global row slices
//  - 2 barriers/chunk; PV overlaps next chunk's band writes
// Grid: 768 blocks (1-D), 256 threads = 4 waves, BM=64.
// ---------------------------------------------------------------------------
__global__ __launch_bounds__(256) void attn_mfma5(
    const ushort* __restrict__ qh, const ushort* __restrict__ kh,
    const ushort* __restrict__ vht, const ushort* __restrict__ posk,
    const ushort* __restrict__ posq, const float* __restrict__ mask,
    float* __restrict__ attn)
{
    __shared__ ushort T1t[128 * 68];     // [u][il]: q_il . posk[d0base+u]
    __shared__ ushort T2t[128 * 68];     // [u][jl]: k_jl . posq[d0base+u]
    __shared__ ushort Ps[4][16][68];     // per-wave P tile (row-major)

    // ---- bn-clustered XCD swizzle (XCD = dispatch_id % 8) ----
    const int id   = blockIdx.x;          // 0..767
    const int xcd  = id & 7;
    const int slot = id >> 3;             // 0..95
    const int bn   = xcd * 3 + (slot >> 5);
    const int i0   = (slot & 31) * 64;
    const int b    = bn / NHEAD;
    const int n    = bn % NHEAD;

    const int tid  = threadIdx.x;
    const int w    = tid >> 6;
    const int lane = tid & 63;
    const int lo   = lane & 15;
    const int hi8  = (lane >> 4) * 8;
    const int g4   = (lane >> 4) * 4;
    const int w16  = w * 16;

    const ushort* qrow = qh + ((size_t)bn * SEQ + i0 + w16 + lo) * 64;
    const bh8 qa0 = *(const bh8*)&qrow[hi8];
    const bh8 qa1 = *(const bh8*)&qrow[32 + hi8];

    const ushort* khb = kh   + (size_t)bn * SEQ * 64;
    const ushort* vtb = vht  + (size_t)bn * 64 * SEQ;
    const ushort* pkh = posk + (size_t)n * SPAN2 * 64;
    const ushort* pqh = posq + (size_t)n * SPAN2 * 64;
    const float*  mrw = mask + (size_t)b * SEQ;

    f32x4 accPV[4] = {};
    float mrow[4] = {-1e30f, -1e30f, -1e30f, -1e30f};
    float lrow[4] = {0.f, 0.f, 0.f, 0.f};

    for (int j0 = 0; j0 < SEQ; j0 += 64) {
        const int d0base = i0 - j0 + 449;       // band row at u=0

        // ---- K A-frags for T2 (this wave's 16 k-rows) ----
        const ushort* krA = khb + (size_t)(j0 + w16 + lo) * 64;
        const bh8 ka0 = *(const bh8*)&krA[hi8];
        const bh8 ka1 = *(const bh8*)&krA[32 + hi8];

        // ---- bands: T1 (q.posk) and T2 (k.posq), transposed stores ----
        #pragma unroll
        for (int tt = 0; tt < 8; ++tt) {
            int r = d0base + tt * 16 + lo;
            r = r < 0 ? 0 : (r > SPAN2 - 1 ? SPAN2 - 1 : r);
            const ushort* pk = pkh + (size_t)r * 64;
            const bh8 pk0 = *(const bh8*)&pk[hi8];
            const bh8 pk1 = *(const bh8*)&pk[32 + hi8];
            f32x4 z1 = {};
            z1 = __builtin_amdgcn_mfma_f32_16x16x32_bf16(qa0, pk0, z1, 0, 0, 0);
            z1 = __builtin_amdgcn_mfma_f32_16x16x32_bf16(qa1, pk1, z1, 0, 0, 0);
            const ushort* pq = pqh + (size_t)r * 64;
            const bh8 pq0 = *(const bh8*)&pq[hi8];
            const bh8 pq1 = *(const bh8*)&pq[32 + hi8];
            f32x4 z2 = {};
            z2 = __builtin_amdgcn_mfma_f32_16x16x32_bf16(ka0, pq0, z2, 0, 0, 0);
            z2 = __builtin_amdgcn_mfma_f32_16x16x32_bf16(ka1, pq1, z2, 0, 0, 0);
            const int u = tt * 16 + lo;
            uint2 w1; w1.x = cvtpk(z1[0], z1[1]); w1.y = cvtpk(z1[2], z1[3]);
            *(uint2*)&T1t[u * 68 + w16 + g4] = w1;
            uint2 w2; w2.x = cvtpk(z2[0], z2[1]); w2.y = cvtpk(z2[2], z2[3]);
            *(uint2*)&T2t[u * 68 + w16 + g4] = w2;
        }

        // ---- S = Q K^T ----
        f32x4 accS[4];
        #pragma unroll
        for (int ct = 0; ct < 4; ++ct) {
            const ushort* kr = khb + (size_t)(j0 + ct * 16 + lo) * 64;
            const bh8 kb0 = *(const bh8*)&kr[hi8];
            const bh8 kb1 = *(const bh8*)&kr[32 + hi8];
            f32x4 z = {};
            z = __builtin_amdgcn_mfma_f32_16x16x32_bf16(qa0, kb0, z, 0, 0, 0);
            accS[ct] = __builtin_amdgcn_mfma_f32_16x16x32_bf16(qa1, kb1, z, 0, 0, 0);
        }

        // ---- mask terms ----
        float maskadd[4];
        #pragma unroll
        for (int ct = 0; ct < 4; ++ct)
            maskadd[ct] = -1e6f * (1.f - mrw[j0 + ct * 16 + lo]);

        __syncthreads();            // barrier 1: T2 (cross-wave) ready

        // ---- gather bias, online softmax (C-frag layout), write P ----
        float corr[4];
        #pragma unroll
        for (int reg = 0; reg < 4; ++reg) {
            const int il = w16 + g4 + reg;
            const int gi = i0 + il;
            float s[4], rmax = -1e30f;
            #pragma unroll
            for (int ct = 0; ct < 4; ++ct) {
                const int jl = ct * 16 + lo;
                const int t  = il - jl + 63;
                float v = accS[ct][reg];
                if (gi >= 1 && (j0 + jl) >= 1)
                    v += b2f(T1t[t * 68 + il]) + b2f(T2t[t * 68 + jl]);
                v += maskadd[ct];
                s[ct] = v;
                rmax = fmaxf(rmax, v);
            }
            rmax = fmaxf(rmax, __shfl_xor(rmax, 1));
            rmax = fmaxf(rmax, __shfl_xor(rmax, 2));
            rmax = fmaxf(rmax, __shfl_xor(rmax, 4));
            rmax = fmaxf(rmax, __shfl_xor(rmax, 8));
            const float mnew = fmaxf(mrow[reg], rmax);
            const float cc   = __expf(mrow[reg] - mnew);
            float psum = 0.f;
            #pragma unroll
            for (int ct = 0; ct < 4; ++ct) {
                const float p = __expf(s[ct] - mnew);
                psum += p;
                Ps[w][g4 + reg][ct * 16 + lo] = f2bf(p);
            }
            psum += __shfl_xor(psum, 1);
            psum += __shfl_xor(psum, 2);
            psum += __shfl_xor(psum, 4);
            psum += __shfl_xor(psum, 8);
            lrow[reg] = lrow[reg] * cc + psum;
            mrow[reg] = mnew;
            corr[reg] = cc;
        }

        __syncthreads();            // barrier 2: T2t reads done -> reusable

        // ---- PV: A = P (own-wave LDS), B = V^T rows (global, L2-hot) ----
        {
            const bh8 pa0 = *(const bh8*)&Ps[w][lo][hi8];
            const bh8 pa1 = *(const bh8*)&Ps[w][lo][32 + hi8];
            #pragma unroll
            for (int dt = 0; dt < 4; ++dt) {
                const ushort* vr = vtb + (size_t)(dt * 16 + lo) * SEQ + j0;
                const bh8 vb0 = *(const bh8*)&vr[hi8];
                const bh8 vb1 = *(const bh8*)&vr[32 + hi8];
                f32x4 a = accPV[dt];
                #pragma unroll
                for (int reg = 0; reg < 4; ++reg) a[reg] *= corr[reg];
                a = __builtin_amdgcn_mfma_f32_16x16x32_bf16(pa0, vb0, a, 0, 0, 0);
                accPV[dt] = __builtin_amdgcn_mfma_f32_16x16x32_bf16(pa1, vb1, a, 0, 0, 0);
            }
        }
    }

    #pragma unroll
    for (int reg = 0; reg < 4; ++reg) {
        const int i = i0 + w16 + g4 + reg;
        const float inv = 1.f / lrow[reg];
        #pragma unroll
        for (int dt = 0; dt < 4; ++dt)
            attn[((size_t)b * SEQ + i) * DMODEL + n * 64 + dt * 16 + lo] =
                accPV[dt][reg] * inv;
    }
}

// ---------------------------------------------------------------------------
// Residual + LayerNorm, in-place on attn buffer.
// ---------------------------------------------------------------------------
__global__ __launch_bounds__(256) void resid_ln(
    float* __restrict__ attn, const float* __restrict__ query,
    const float* __restrict__ gamma, const float* __restrict__ beta)
{
    const int b = blockIdx.y;
    const int i = blockIdx.x;
    const size_t base = ((size_t)b * SEQ + i) * DMODEL;
    const int tid = threadIdx.x;

    float x[3];
    #pragma unroll
    for (int s = 0; s < 3; ++s) x[s] = attn[base + s * 256 + tid];

    float sum = x[0] + x[1] + x[2];
    float sq  = x[0]*x[0] + x[1]*x[1] + x[2]*x[2];
    #pragma unroll
    for (int off = 32; off; off >>= 1) {
        sum += __shfl_xor(sum, off);
        sq  += __shfl_xor(sq, off);
    }
    __shared__ float red[2][4];
    const int w = tid >> 6;
    if ((tid & 63) == 0) { red[0][w] = sum; red[1][w] = sq; }
    __syncthreads();
    sum = red[0][0] + red[0][1] + red[0][2] + red[0][3];
    sq  = red[1][0] + red[1][1] + red[1][2] + red[1][3];

    const float mu  = sum * (1.f / DMODEL);
    const float var = sq * (1.f / DMODEL) - mu * mu;
    const float inv = rsqrtf(var + 1e-5f);

    #pragma unroll
    for (int s = 0; s < 3; ++s) {
        const int c = s * 256 + tid;
        attn[base + c] = query[base + c] + (x[s] - mu) * inv * gamma[c] + beta[c];
    }
}

// ---------------------------------------------------------------------------
extern "C" void kernel_launch(void* const* d_in, const int* in_sizes, int n_in,
                              void* d_out, int out_size, void* d_ws, size_t ws_size,
                              hipStream_t stream)
{
    const float* query = (const float*)d_in[0];
    const float* mask  = (const float*)d_in[1];
    const float* pke   = (const float*)d_in[2];
    const float* pqe   = (const float*)d_in[3];
    const float* Wq    = (const float*)d_in[4];
    const float* bq    = (const float*)d_in[5];
    const float* Wk    = (const float*)d_in[6];
    const float* Wv    = (const float*)d_in[7];
    const float* bv    = (const float*)d_in[8];
    const float* Wpq   = (const float*)d_in[9];
    const float* bpq   = (const float*)d_in[10];
    const float* Wpk   = (const float*)d_in[11];
    const float* rwb   = (const float*)d_in[12];
    const float* gamma = (const float*)d_in[13];
    const float* beta  = (const float*)d_in[14];

    float* out = (float*)d_out;

    const int Q_N  = NB * SEQ * DMODEL;
    const int P_N  = SPAN2 * DMODEL;
    const int W_N  = DMODEL * DMODEL;
    const size_t QKV_ELEMS = (size_t)NB * NHEAD * SEQ * 64;
    const size_t POS_ELEMS = (size_t)NHEAD * SPAN2 * 64;

    ushort* xb   = (ushort*)d_ws;
    ushort* pkeb = xb   + Q_N;
    ushort* pqeb = pkeb + P_N;
    ushort* wqb  = pqeb + P_N;
    ushort* wkb  = wqb  + W_N;
    ushort* wvb  = wkb  + W_N;
    ushort* wpqb = wvb  + W_N;
    ushort* wpkb = wpqb + W_N;
    ushort* qh   = wpkb + W_N;
    ushort* kh   = qh   + QKV_ELEMS;
    ushort* vht  = kh   + QKV_ELEMS;
    ushort* pkp  = vht  + QKV_ELEMS;
    ushort* pqp  = pkp  + POS_ELEMS;

    dim3 blk(256);

    CvtArgs ca;
    ca.src[0] = query; ca.dst[0] = xb;   ca.n[0] = Q_N;
    ca.src[1] = pke;   ca.dst[1] = pkeb; ca.n[1] = P_N;
    ca.src[2] = pqe;   ca.dst[2] = pqeb; ca.n[2] = P_N;
    ca.src[3] = Wq;    ca.dst[3] = wqb;  ca.n[3] = W_N;
    ca.src[4] = Wk;    ca.dst[4] = wkb;  ca.n[4] = W_N;
    ca.src[5] = Wv;    ca.dst[5] = wvb;  ca.n[5] = W_N;
    ca.src[6] = Wpq;   ca.dst[6] = wpqb; ca.n[6] = W_N;
    ca.src[7] = Wpk;   ca.dst[7] = wpkb; ca.n[7] = W_N;
    cvt_bf16<<<dim3((Q_N / 8 + 255) / 256, 8), blk, 0, stream>>>(ca);

    // projections
    proj_mfma<<<dim3(128, NHEAD), blk, 0, stream>>>(xb,   wqb,  bq,  rwb, SCALEF, SEQ,   qh,  nullptr);
    proj_mfma<<<dim3(128, NHEAD), blk, 0, stream>>>(xb,   wkb,  nullptr, nullptr, 1.f, SEQ, kh, nullptr);
    proj_mfma<<<dim3(128, NHEAD), blk, 0, stream>>>(xb,   wvb,  bv,  nullptr, 1.f,   SEQ,   nullptr, vht);
    proj_mfma<<<dim3(32,  NHEAD), blk, 0, stream>>>(pkeb, wpkb, nullptr, nullptr, 1.f, SPAN2, pkp, nullptr);
    proj_mfma<<<dim3(32,  NHEAD), blk, 0, stream>>>(pqeb, wpqb, bpq, nullptr, SCALEF, SPAN2, pqp, nullptr);

    // fused attention (single S x S pass) -> d_out as [B,S,768] attn_vec (f32)
    attn_mfma5<<<dim3(NB * NHEAD * (SEQ / 64)), blk, 0, stream>>>(
        qh, kh, vht, pkp, pqp, mask, out);

    // residual + LN in-place
    resid_ln<<<dim3(SEQ, NB), blk, 0, stream>>>(out, query, gamma, beta);
}

// Round 7
// 301.256 us; speedup vs baseline: 2.2193x; 2.0535x over previous
//
#include <hip/hip_runtime.h>
#include <math.h>

#define NB     2
#define SEQ    2048
#define NHEAD  12
#define DMODEL 768
#define SPAN2  1024
#define SCALEF 0.07216878364870323f   // 1/sqrt(192)

typedef unsigned short ushort;
typedef unsigned int   uint;
typedef __attribute__((ext_vector_type(8))) short  bh8;   // 8 x bf16
typedef __attribute__((ext_vector_type(4))) float  f32x4; // MFMA C/D frag
typedef __attribute__((ext_vector_type(4))) unsigned short us4;

__device__ inline ushort f2bf(float x) {            // RNE f32 -> bf16
    uint u = __builtin_bit_cast(uint, x);
    u += 0x7FFFu + ((u >> 16) & 1u);
    return (ushort)(u >> 16);
}
__device__ inline float b2f(ushort h) {
    uint u = ((uint)h) << 16;
    return __builtin_bit_cast(float, u);
}
__device__ inline uint cvtpk(float a, float b) {    // 2xf32 -> packed bf16x2
    uint r;
    asm("v_cvt_pk_bf16_f32 %0, %1, %2" : "=v"(r) : "v"(a), "v"(b));
    return r;
}

// async global->LDS, 16B per lane; LDS dest = wave-uniform base + lane*16
__device__ __forceinline__ void gld16(const ushort* g, ushort* l) {
    __builtin_amdgcn_global_load_lds(
        (const __attribute__((address_space(1))) void*)g,
        (__attribute__((address_space(3))) void*)l, 16, 0, 0);
}

// swizzled b128 LDS fragment read: tile rows of 128B, 16B slots, slot^=(row&7)
__device__ __forceinline__ bh8 ldsfrag(const ushort* tile, int row, int slot) {
    return *(const bh8*)((const char*)tile + row * 128 + (((slot ^ (row & 7)) << 4)));
}

// ---------------------------------------------------------------------------
// Multi-segment f32 -> bf16 convert.
// ---------------------------------------------------------------------------
struct CvtArgs {
    const float* src[8];
    ushort*      dst[8];
    int          n[8];
};

__global__ __launch_bounds__(256) void cvt_bf16(CvtArgs a)
{
    const int seg = blockIdx.y;
    const int i   = (blockIdx.x * 256 + threadIdx.x) * 8;
    if (i >= a.n[seg]) return;
    const float4* s = (const float4*)(a.src[seg] + i);
    const float4 x = s[0], y = s[1];
    bh8 o;
    o[0] = (short)f2bf(x.x); o[1] = (short)f2bf(x.y);
    o[2] = (short)f2bf(x.z); o[3] = (short)f2bf(x.w);
    o[4] = (short)f2bf(y.x); o[5] = (short)f2bf(y.y);
    o[6] = (short)f2bf(y.z); o[7] = (short)f2bf(y.w);
    *(bh8*)(a.dst[seg] + i) = o;
}

// ---------------------------------------------------------------------------
// LDS-staged MFMA projection GEMM:  out = (X @ W^T + b1 + b2) * scale
// Block = 32(M) x 64(N), 4 waves (wr=w&1 row strip, wc=w>>1 col half).
// All global reads dense via global_load_lds + XOR swizzle.
// ---------------------------------------------------------------------------
__global__ __launch_bounds__(256) void proj_mfma2(
    const ushort* __restrict__ X, const ushort* __restrict__ W,
    const float* __restrict__ b1, const float* __restrict__ b2,
    float scale, int rowsPerBatch,
    ushort* __restrict__ out, ushort* __restrict__ outT)
{
    __shared__ ushort Xs[32 * 64];     // 4KB
    __shared__ ushort Ws[64 * 64];     // 8KB
    const int r0 = blockIdx.x * 32;
    const int n  = blockIdx.y;
    const int c0 = n * 64;
    const int tid  = threadIdx.x;
    const int w    = tid >> 6;
    const int lane = tid & 63;
    const int lo   = lane & 15;
    const int hi8  = (lane >> 4) * 8;
    const int g4   = (lane >> 4) * 4;
    const int wr   = w & 1;
    const int wc   = w >> 1;
    const int r8   = lane >> 3;
    const int sl   = lane & 7;

    f32x4 acc[2] = {};
    for (int k0 = 0; k0 < DMODEL; k0 += 64) {
        {   // stage X tile [32][64]
            const int r = w * 8 + r8;
            const int s = sl ^ (r & 7);
            gld16(X + (size_t)(r0 + r) * DMODEL + k0 + s * 8, Xs + w * 512);
        }
        #pragma unroll
        for (int i = 0; i < 2; ++i) {   // stage W tile [64][64]
            const int c = i * 4 + w;
            const int r = c * 8 + r8;
            const int s = sl ^ (r & 7);
            gld16(W + (size_t)(c0 + r) * DMODEL + k0 + s * 8, Ws + c * 512);
        }
        __syncthreads();
        const bh8 a0 = ldsfrag(Xs, wr * 16 + lo, hi8 >> 3);
        const bh8 a1 = ldsfrag(Xs, wr * 16 + lo, 4 + (hi8 >> 3));
        #pragma unroll
        for (int ct = 0; ct < 2; ++ct) {
            const int row = wc * 32 + ct * 16 + lo;
            const bh8 wb0 = ldsfrag(Ws, row, hi8 >> 3);
            const bh8 wb1 = ldsfrag(Ws, row, 4 + (hi8 >> 3));
            acc[ct] = __builtin_amdgcn_mfma_f32_16x16x32_bf16(a0, wb0, acc[ct], 0, 0, 0);
            acc[ct] = __builtin_amdgcn_mfma_f32_16x16x32_bf16(a1, wb1, acc[ct], 0, 0, 0);
        }
        __syncthreads();
    }

    const int rbase = r0 + wr * 16 + g4;
    const int bb  = rbase / rowsPerBatch;
    const int rr0 = rbase - bb * rowsPerBatch;
    #pragma unroll
    for (int ct = 0; ct < 2; ++ct) {
        const int d = wc * 32 + ct * 16 + lo;
        const int c = c0 + d;
        const float badd = (b1 ? b1[c] : 0.f) + (b2 ? b2[c] : 0.f);
        if (out) {
            #pragma unroll
            for (int reg = 0; reg < 4; ++reg)
                out[(((size_t)bb * NHEAD + n) * rowsPerBatch + rr0 + reg) * 64 + d] =
                    f2bf((acc[ct][reg] + badd) * scale);
        }
        if (outT) {
            us4 o;
            #pragma unroll
            for (int reg = 0; reg < 4; ++reg)
                o[reg] = f2bf((acc[ct][reg] + badd) * scale);
            *(us4*)&outT[(((size_t)bb * NHEAD + n) * 64 + d) * rowsPerBatch + rr0] = o;
        }
    }
}

// ---------------------------------------------------------------------------
// Fused MFMA flash attention v6: ALL fragment sources staged dense into LDS
// via global_load_lds (+XOR swizzle). Pos bands (128 contiguous rows), K, and
// V^T (aliased into K buffer after K's last read) staged per chunk. Band
// product tables T1/T2 in LDS with 8B-granular swizzle. 4 barriers/chunk.
// LDS 79.75KB -> 2 blocks/CU. Grid 768, bn-clustered XCD swizzle.
// ---------------------------------------------------------------------------
__global__ __launch_bounds__(256) void attn_mfma6(
    const ushort* __restrict__ qh, const ushort* __restrict__ kh,
    const ushort* __restrict__ vht, const ushort* __restrict__ posk,
    const ushort* __restrict__ posq, const float* __restrict__ mask,
    float* __restrict__ attn)
{
    __shared__ ushort PKs[128 * 64];      // 16KB posk band rows d0base..+127
    __shared__ ushort PQs[128 * 64];      // 16KB posq band
    __shared__ ushort KV [64 * 64];       // 8KB: K chunk, then V^T chunk
    __shared__ ushort T1t[127 * 64];      // 15.9KB [t][il], 8B-swz
    __shared__ ushort T2t[127 * 64];      // 15.9KB [t][jl], 8B-swz
    __shared__ ushort Ps [4][16 * 64];    // 8KB per-wave P, 16B-swz

    const int id   = blockIdx.x;          // 0..767, bn-clustered XCD swizzle
    const int xcd  = id & 7;
    const int slot = id >> 3;
    const int bn   = xcd * 3 + (slot >> 5);
    const int i0   = (slot & 31) * 64;
    const int b    = bn / NHEAD;
    const int n    = bn % NHEAD;

    const int tid  = threadIdx.x;
    const int w    = tid >> 6;
    const int lane = tid & 63;
    const int lo   = lane & 15;
    const int hi8  = (lane >> 4) * 8;
    const int g4   = (lane >> 4) * 4;
    const int w16  = w * 16;
    const int r8   = lane >> 3;
    const int sl   = lane & 7;
    const int slotA = hi8 >> 3;           // 0..3

    const ushort* qrow = qh + ((size_t)bn * SEQ + i0 + w16 + lo) * 64;
    const bh8 qa0 = *(const bh8*)&qrow[hi8];
    const bh8 qa1 = *(const bh8*)&qrow[32 + hi8];

    const ushort* khb = kh   + (size_t)bn * SEQ * 64;
    const ushort* vtb = vht  + (size_t)bn * 64 * SEQ;
    const ushort* pkh = posk + (size_t)n * SPAN2 * 64;
    const ushort* pqh = posq + (size_t)n * SPAN2 * 64;
    const float*  mrw = mask + (size_t)b * SEQ;

    f32x4 accPV[4] = {};
    float mrow[4] = {-1e30f, -1e30f, -1e30f, -1e30f};
    float lrow[4] = {0.f, 0.f, 0.f, 0.f};

    for (int j0 = 0; j0 < SEQ; j0 += 64) {
        const int d0base = i0 - j0 + 449;          // band row at u=0

        // ---- stage K + pos bands (dense, swizzled source) ----
        #pragma unroll
        for (int i = 0; i < 2; ++i) {
            const int c = i * 4 + w;
            const int r = c * 8 + r8;
            const int s = sl ^ (r & 7);
            gld16(khb + (size_t)(j0 + r) * 64 + s * 8, KV + c * 512);
        }
        #pragma unroll
        for (int i = 0; i < 4; ++i) {
            const int c = i * 4 + w;
            const int r = c * 8 + r8;              // 0..127
            const int s = sl ^ (r & 7);
            int gr = d0base + r; gr = gr < 0 ? 0 : (gr > SPAN2 - 1 ? SPAN2 - 1 : gr);
            gld16(pkh + (size_t)gr * 64 + s * 8, PKs + c * 512);
            gld16(pqh + (size_t)gr * 64 + s * 8, PQs + c * 512);
        }
        __syncthreads();   // B1: staging complete

        // ---- K A-frags for T2 (this wave's 16 k-rows) ----
        const bh8 ka0 = ldsfrag(KV, w16 + lo, slotA);
        const bh8 ka1 = ldsfrag(KV, w16 + lo, 4 + slotA);

        // ---- band MFMAs: T1 = Q.poskband^T, T2 = K.posqband^T ----
        #pragma unroll
        for (int tt = 0; tt < 8; ++tt) {
            const int u = tt * 16 + lo;
            const bh8 pk0 = ldsfrag(PKs, u, slotA);
            const bh8 pk1 = ldsfrag(PKs, u, 4 + slotA);
            f32x4 z1 = {};
            z1 = __builtin_amdgcn_mfma_f32_16x16x32_bf16(qa0, pk0, z1, 0, 0, 0);
            z1 = __builtin_amdgcn_mfma_f32_16x16x32_bf16(qa1, pk1, z1, 0, 0, 0);
            const bh8 pq0 = ldsfrag(PQs, u, slotA);
            const bh8 pq1 = ldsfrag(PQs, u, 4 + slotA);
            f32x4 z2 = {};
            z2 = __builtin_amdgcn_mfma_f32_16x16x32_bf16(ka0, pq0, z2, 0, 0, 0);
            z2 = __builtin_amdgcn_mfma_f32_16x16x32_bf16(ka1, pq1, z2, 0, 0, 0);
            if (u < 127) {                          // t range is [0,126]
                const int cb = (w16 + g4) * 2;      // 8B-aligned col byte
                uint2 w1; w1.x = cvtpk(z1[0], z1[1]); w1.y = cvtpk(z1[2], z1[3]);
                *(uint2*)((char*)T1t + u * 128 + (cb ^ ((u & 15) * 8))) = w1;
                uint2 w2; w2.x = cvtpk(z2[0], z2[1]); w2.y = cvtpk(z2[2], z2[3]);
                *(uint2*)((char*)T2t + u * 128 + (cb ^ ((u & 15) * 8))) = w2;
            }
        }

        // ---- S = Q K^T ----
        f32x4 accS[4];
        #pragma unroll
        for (int ct = 0; ct < 4; ++ct) {
            const bh8 kb0 = ldsfrag(KV, ct * 16 + lo, slotA);
            const bh8 kb1 = ldsfrag(KV, ct * 16 + lo, 4 + slotA);
            f32x4 z = {};
            z = __builtin_amdgcn_mfma_f32_16x16x32_bf16(qa0, kb0, z, 0, 0, 0);
            accS[ct] = __builtin_amdgcn_mfma_f32_16x16x32_bf16(qa1, kb1, z, 0, 0, 0);
        }

        float maskadd[4];
        #pragma unroll
        for (int ct = 0; ct < 4; ++ct)
            maskadd[ct] = -1e6f * (1.f - mrw[j0 + ct * 16 + lo]);

        __syncthreads();   // B2: T tables ready, K reads done

        // ---- stage V^T into KV (overlaps softmax) ----
        #pragma unroll
        for (int i = 0; i < 2; ++i) {
            const int c = i * 4 + w;
            const int r = c * 8 + r8;              // d row 0..63
            const int s = sl ^ (r & 7);
            gld16(vtb + (size_t)r * SEQ + j0 + s * 8, KV + c * 512);
        }

        // ---- online softmax on C-frag layout; gathers from T1/T2 ----
        float corr[4];
        char* pbase = (char*)&Ps[w][0];
        #pragma unroll
        for (int reg = 0; reg < 4; ++reg) {
            const int il = w16 + g4 + reg;
            const int gi = i0 + il;
            float s[4], rmax = -1e30f;
            #pragma unroll
            for (int ct = 0; ct < 4; ++ct) {
                const int jl = ct * 16 + lo;
                const int t  = il - jl + 63;
                float v = accS[ct][reg];
                if (gi >= 1 && (j0 + jl) >= 1) {
                    const ushort t1 = *(const ushort*)((const char*)T1t + t * 128 + ((il * 2) ^ ((t & 15) * 8)));
                    const ushort t2 = *(const ushort*)((const char*)T2t + t * 128 + ((jl * 2) ^ ((t & 15) * 8)));
                    v += b2f(t1) + b2f(t2);
                }
                v += maskadd[ct];
                s[ct] = v;
                rmax = fmaxf(rmax, v);
            }
            rmax = fmaxf(rmax, __shfl_xor(rmax, 1));
            rmax = fmaxf(rmax, __shfl_xor(rmax, 2));
            rmax = fmaxf(rmax, __shfl_xor(rmax, 4));
            rmax = fmaxf(rmax, __shfl_xor(rmax, 8));
            const float mnew = fmaxf(mrow[reg], rmax);
            const float cc   = __expf(mrow[reg] - mnew);
            float psum = 0.f;
            const int prow = g4 + reg;
            #pragma unroll
            for (int ct = 0; ct < 4; ++ct) {
                const float p = __expf(s[ct] - mnew);
                psum += p;
                *(ushort*)(pbase + prow * 128 + ((((ct * 16 + lo) * 2)) ^ ((prow & 7) * 16))) = f2bf(p);
            }
            psum += __shfl_xor(psum, 1);
            psum += __shfl_xor(psum, 2);
            psum += __shfl_xor(psum, 4);
            psum += __shfl_xor(psum, 8);
            lrow[reg] = lrow[reg] * cc + psum;
            mrow[reg] = mnew;
            corr[reg] = cc;
        }

        __syncthreads();   // B3: V^T staged (DMA drained)

        // ---- PV: A = P (swizzled LDS), B = V^T rows (swizzled LDS) ----
        {
            const bh8 pa0 = *(const bh8*)(pbase + lo * 128 + ((slotA << 4) ^ ((lo & 7) * 16)));
            const bh8 pa1 = *(const bh8*)(pbase + lo * 128 + (((4 + slotA) << 4) ^ ((lo & 7) * 16)));
            #pragma unroll
            for (int dt = 0; dt < 4; ++dt) {
                const bh8 vb0 = ldsfrag(KV, dt * 16 + lo, slotA);
                const bh8 vb1 = ldsfrag(KV, dt * 16 + lo, 4 + slotA);
                f32x4 a = accPV[dt];
                #pragma unroll
                for (int reg = 0; reg < 4; ++reg) a[reg] *= corr[reg];
                a = __builtin_amdgcn_mfma_f32_16x16x32_bf16(pa0, vb0, a, 0, 0, 0);
                accPV[dt] = __builtin_amdgcn_mfma_f32_16x16x32_bf16(pa1, vb1, a, 0, 0, 0);
            }
        }
        __syncthreads();   // B4: all LDS reads done before next chunk's staging
    }

    #pragma unroll
    for (int reg = 0; reg < 4; ++reg) {
        const int i = i0 + w16 + g4 + reg;
        const float inv = 1.f / lrow[reg];
        #pragma unroll
        for (int dt = 0; dt < 4; ++dt)
            attn[((size_t)b * SEQ + i) * DMODEL + n * 64 + dt * 16 + lo] =
                accPV[dt][reg] * inv;
    }
}

// ---------------------------------------------------------------------------
// Residual + LayerNorm, in-place on attn buffer.
// ---------------------------------------------------------------------------
__global__ __launch_bounds__(256) void resid_ln(
    float* __restrict__ attn, const float* __restrict__ query,
    const float* __restrict__ gamma, const float* __restrict__ beta)
{
    const int b = blockIdx.y;
    const int i = blockIdx.x;
    const size_t base = ((size_t)b * SEQ + i) * DMODEL;
    const int tid = threadIdx.x;

    float x[3];
    #pragma unroll
    for (int s = 0; s < 3; ++s) x[s] = attn[base + s * 256 + tid];

    float sum = x[0] + x[1] + x[2];
    float sq  = x[0]*x[0] + x[1]*x[1] + x[2]*x[2];
    #pragma unroll
    for (int off = 32; off; off >>= 1) {
        sum += __shfl_xor(sum, off);
        sq  += __shfl_xor(sq, off);
    }
    __shared__ float red[2][4];
    const int w = tid >> 6;
    if ((tid & 63) == 0) { red[0][w] = sum; red[1][w] = sq; }
    __syncthreads();
    sum = red[0][0] + red[0][1] + red[0][2] + red[0][3];
    sq  = red[1][0] + red[1][1] + red[1][2] + red[1][3];

    const float mu  = sum * (1.f / DMODEL);
    const float var = sq * (1.f / DMODEL) - mu * mu;
    const float inv = rsqrtf(var + 1e-5f);

    #pragma unroll
    for (int s = 0; s < 3; ++s) {
        const int c = s * 256 + tid;
        attn[base + c] = query[base + c] + (x[s] - mu) * inv * gamma[c] + beta[c];
    }
}

// ---------------------------------------------------------------------------
extern "C" void kernel_launch(void* const* d_in, const int* in_sizes, int n_in,
                              void* d_out, int out_size, void* d_ws, size_t ws_size,
                              hipStream_t stream)
{
    const float* query = (const float*)d_in[0];
    const float* mask  = (const float*)d_in[1];
    const float* pke   = (const float*)d_in[2];
    const float* pqe   = (const float*)d_in[3];
    const float* Wq    = (const float*)d_in[4];
    const float* bq    = (const float*)d_in[5];
    const float* Wk    = (const float*)d_in[6];
    const float* Wv    = (const float*)d_in[7];
    const float* bv    = (const float*)d_in[8];
    const float* Wpq   = (const float*)d_in[9];
    const float* bpq   = (const float*)d_in[10];
    const float* Wpk   = (const float*)d_in[11];
    const float* rwb   = (const float*)d_in[12];
    const float* gamma = (const float*)d_in[13];
    const float* beta  = (const float*)d_in[14];

    float* out = (float*)d_out;

    const int Q_N  = NB * SEQ * DMODEL;
    const int P_N  = SPAN2 * DMODEL;
    const int W_N  = DMODEL * DMODEL;
    const size_t QKV_ELEMS = (size_t)NB * NHEAD * SEQ * 64;
    const size_t POS_ELEMS = (size_t)NHEAD * SPAN2 * 64;

    ushort* xb   = (ushort*)d_ws;
    ushort* pkeb = xb   + Q_N;
    ushort* pqeb = pkeb + P_N;
    ushort* wqb  = pqeb + P_N;
    ushort* wkb  = wqb  + W_N;
    ushort* wvb  = wkb  + W_N;
    ushort* wpqb = wvb  + W_N;
    ushort* wpkb = wpqb + W_N;
    ushort* qh   = wpkb + W_N;
    ushort* kh   = qh   + QKV_ELEMS;
    ushort* vht  = kh   + QKV_ELEMS;
    ushort* pkp  = vht  + QKV_ELEMS;
    ushort* pqp  = pkp  + POS_ELEMS;

    dim3 blk(256);

    CvtArgs ca;
    ca.src[0] = query; ca.dst[0] = xb;   ca.n[0] = Q_N;
    ca.src[1] = pke;   ca.dst[1] = pkeb; ca.n[1] = P_N;
    ca.src[2] = pqe;   ca.dst[2] = pqeb; ca.n[2] = P_N;
    ca.src[3] = Wq;    ca.dst[3] = wqb;  ca.n[3] = W_N;
    ca.src[4] = Wk;    ca.dst[4] = wkb;  ca.n[4] = W_N;
    ca.src[5] = Wv;    ca.dst[5] = wvb;  ca.n[5] = W_N;
    ca.src[6] = Wpq;   ca.dst[6] = wpqb; ca.n[6] = W_N;
    ca.src[7] = Wpk;   ca.dst[7] = wpkb; ca.n[7] = W_N;
    cvt_bf16<<<dim3((Q_N / 8 + 255) / 256, 8), blk, 0, stream>>>(ca);

    // projections (LDS-staged, dense)
    proj_mfma2<<<dim3(128, NHEAD), blk, 0, stream>>>(xb,   wqb,  bq,  rwb, SCALEF, SEQ,   qh,  nullptr);
    proj_mfma2<<<dim3(128, NHEAD), blk, 0, stream>>>(xb,   wkb,  nullptr, nullptr, 1.f, SEQ, kh, nullptr);
    proj_mfma2<<<dim3(128, NHEAD), blk, 0, stream>>>(xb,   wvb,  bv,  nullptr, 1.f,   SEQ,   nullptr, vht);
    proj_mfma2<<<dim3(32,  NHEAD), blk, 0, stream>>>(pkeb, wpkb, nullptr, nullptr, 1.f, SPAN2, pkp, nullptr);
    proj_mfma2<<<dim3(32,  NHEAD), blk, 0, stream>>>(pqeb, wpqb, bpq, nullptr, SCALEF, SPAN2, pqp, nullptr);

    // fused attention (single S x S pass, dense-staged) -> d_out
    attn_mfma6<<<dim3(NB * NHEAD * (SEQ / 64)), blk, 0, stream>>>(
        qh, kh, vht, pkp, pqp, mask, out);

    // residual + LN in-place
    resid_ln<<<dim3(SEQ, NB), blk, 0, stream>>>(out, query, gamma, beta);
}